// Round 9
// baseline (274.473 us; speedup 1.0000x reference)
//
#include <hip/hip_runtime.h>
#include <cmath>

#define NQ 16
#define NT 8

typedef float f32x4 __attribute__((ext_vector_type(4)));

// order-preserving float->u32 (total order ascending)
__device__ __forceinline__ unsigned ordf(float x) {
    unsigned u = __float_as_uint(x);
    return u ^ ((unsigned)((int)u >> 31) | 0x80000000u);
}
// inverse; 0xFFFFFFFF (empty sentinel) -> NaN so ordered compares are false
__device__ __forceinline__ float unordf(unsigned k) {
    unsigned m = (~(unsigned)((int)k >> 31)) | 0x80000000u;
    return __uint_as_float(k ^ m);
}
__device__ __forceinline__ unsigned umin2(unsigned a, unsigned b) { return a < b ? a : b; }
__device__ __forceinline__ unsigned umax2(unsigned a, unsigned b) { return a > b ? a : b; }

// Exact reference-parity path (rare): correctly-rounded double-exp sigmoid,
// exact float dedup. Validated bit-exact (absmax 0.0) in R1/R3/R6/R7/R8.
__device__ __noinline__ unsigned exact_mask(
    const float* __restrict__ pred_logits,
    const float* __restrict__ pred_disp,
    const float* __restrict__ targets,
    size_t b)
{
    float tg[NT];
#pragma unroll
    for (int t = 0; t < NT; ++t) {
        float v = targets[b * NT + t];
        tg[t] = (v == 0.0f) ? 1000000.0f : v;
    }
    float C[NQ];
    int   ind[NQ];
#pragma unroll
    for (int n = 0; n < NQ; ++n) {
        float d = pred_disp[b * NQ + n];
        float best = fabsf(d - tg[0]);
        int bi = 0;
#pragma unroll
        for (int t = 1; t < NT; ++t) {
            float e = fabsf(d - tg[t]);
            if (e < best) { best = e; bi = t; }
        }
        float sig = (float)(1.0 / (1.0 + exp(-(double)pred_logits[b * NQ + n])));
        C[n] = (-sig) + best;
        ind[n] = bi;
    }
    unsigned mask = 0u;
#pragma unroll
    for (int t = 0; t < NT; ++t) {
        int w = 31;
        float bc = 3.0e38f;
#pragma unroll
        for (int n = 0; n < NQ; ++n) {
            bool upd = (ind[n] == t) && (C[n] < bc);
            bc = upd ? C[n] : bc;
            w  = upd ? n : w;
        }
        mask |= (1u << w);
    }
    return mask;
}

// Quad compute for one row (verified in R8): lane j owns queries 4j..4j+3.
// tg[8] must already be sentinel-replaced and identical across the quad.
__device__ __forceinline__ void quad_row(
    f32x4 d4, f32x4 l4, const float tg[NT], int j,
    int ind[4], unsigned* out_mask, bool* out_slow)
{
    unsigned qk[4];
    {
        float dv[4] = {d4.x, d4.y, d4.z, d4.w};
        float lv[4] = {l4.x, l4.y, l4.z, l4.w};
#pragma unroll
        for (int i = 0; i < 4; ++i) {
            float d = dv[i];
            float best = fabsf(d - tg[0]);
            int bi = 0;
#pragma unroll
            for (int t = 1; t < NT; ++t) {
                float e = fabsf(d - tg[t]);
                if (e < best) { best = e; bi = t; }   // exact argmin, matches ref
            }
            ind[i] = bi;
            float sig = __builtin_amdgcn_rcpf(1.0f + __expf(-lv[i]));
            float C = best - sig;
            qk[i] = (ordf(C) & ~31u) | (unsigned)(4 * j + i);
        }
    }
    unsigned mask = 0u;
    bool need_slow = false;
#pragma unroll
    for (int t = 0; t < NT; ++t) {
        unsigned bc = 0xFFFFFFFFu, bc2 = 0xFFFFFFFFu;
#pragma unroll
        for (int i = 0; i < 4; ++i) {
            unsigned x = (ind[i] == t) ? qk[i] : 0xFFFFFFFFu;
            unsigned hi = umax2(bc, x);
            bc  = umin2(bc, x);
            bc2 = umin2(bc2, hi);
        }
#pragma unroll
        for (int r = 1; r <= 2; r <<= 1) {
            unsigned ob  = __shfl_xor(bc,  r, 4);
            unsigned ob2 = __shfl_xor(bc2, r, 4);
            unsigned hi  = umax2(bc, ob);
            bc  = umin2(bc, ob);
            bc2 = umin2(umin2(bc2, ob2), hi);
        }
        float bcf  = unordf(bc);     // empty/singleton -> NaN -> compares false
        float bc2f = unordf(bc2);
        float thr  = fmaf(fabsf(bcf), 1.6e-5f, 2.0e-4f);
        need_slow = need_slow || ((bc2f - bcf) < thr);
        mask |= (1u << (bc & 31u));  // empty -> bit 31, ignored by label read
    }
    *out_mask = mask;
    *out_slow = need_slow;
}

__device__ __forceinline__ void quad_targets(
    const float* __restrict__ targets, size_t b, int j, float tg[NT])
{
    f32x4 t4 = ((const f32x4*)targets)[b * 2 + (size_t)(j & 1)];
    float tv[4] = {t4.x, t4.y, t4.z, t4.w};
#pragma unroll
    for (int i = 0; i < 4; ++i) tv[i] = (tv[i] == 0.0f) ? 1000000.0f : tv[i];
    float ov[4];
#pragma unroll
    for (int i = 0; i < 4; ++i) ov[i] = __shfl_xor(tv[i], 1, 4);
    if ((j & 1) == 0) {
#pragma unroll
        for (int i = 0; i < 4; ++i) { tg[i] = tv[i]; tg[4 + i] = ov[i]; }
    } else {
#pragma unroll
        for (int i = 0; i < 4; ++i) { tg[i] = ov[i]; tg[4 + i] = tv[i]; }
    }
}

// Each thread: TWO rows (q and q+Bh), all loads issued up front -> 2x in-flight
// bytes per wave, half the waves of R8. All global IO 16 B/lane contiguous.
__global__ __launch_bounds__(256) void nearest_matcher_kernel(
    const float* __restrict__ pred_logits,
    const float* __restrict__ pred_disp,
    const float* __restrict__ targets,
    float* __restrict__ out_idx,
    float* __restrict__ out_lab,
    int B)
{
    const size_t Bh  = ((size_t)B + 1) / 2;
    const size_t tid = (size_t)blockIdx.x * blockDim.x + threadIdx.x;
    const size_t q   = tid >> 2;          // row A id; row B = q + Bh
    const int    j   = (int)(tid & 3);
    if (q >= Bh) return;

    const size_t bA = q;
    const size_t bB = q + Bh;
    const bool hasB = (bB < (size_t)B);

    // ---- issue ALL loads up front (6 independent streams) ----
    f32x4 dA = ((const f32x4*)pred_disp  )[bA * 4 + (size_t)j];
    f32x4 lA = ((const f32x4*)pred_logits)[bA * 4 + (size_t)j];
    f32x4 dB{}, lB{};
    if (hasB) {
        dB = ((const f32x4*)pred_disp  )[bB * 4 + (size_t)j];
        lB = ((const f32x4*)pred_logits)[bB * 4 + (size_t)j];
    }

    float tgA[NT], tgB[NT];
    quad_targets(targets, bA, j, tgA);
    if (hasB) quad_targets(targets, bB, j, tgB);

    // ---- row A ----
    int indA[4]; unsigned maskA; bool slowA;
    quad_row(dA, lA, tgA, j, indA, &maskA, &slowA);
    // ---- row B ----
    int indB[4] = {0,0,0,0}; unsigned maskB = 0; bool slowB = false;
    if (hasB) quad_row(dB, lB, tgB, j, indB, &maskB, &slowB);

    if (__builtin_expect(slowA, 0))
        maskA = exact_mask(pred_logits, pred_disp, targets, bA);
    if (__builtin_expect(slowB, 0))
        maskB = exact_mask(pred_logits, pred_disp, targets, bB);

    // ---- emit (all 16 B/lane contiguous) ----
    {
        f32x4 oi, ol;
        oi.x = (float)indA[0]; oi.y = (float)indA[1];
        oi.z = (float)indA[2]; oi.w = (float)indA[3];
        ol.x = (float)((maskA >> (4 * j + 0)) & 1u);
        ol.y = (float)((maskA >> (4 * j + 1)) & 1u);
        ol.z = (float)((maskA >> (4 * j + 2)) & 1u);
        ol.w = (float)((maskA >> (4 * j + 3)) & 1u);
        ((f32x4*)out_idx)[bA * 4 + (size_t)j] = oi;
        ((f32x4*)out_lab)[bA * 4 + (size_t)j] = ol;
    }
    if (hasB) {
        f32x4 oi, ol;
        oi.x = (float)indB[0]; oi.y = (float)indB[1];
        oi.z = (float)indB[2]; oi.w = (float)indB[3];
        ol.x = (float)((maskB >> (4 * j + 0)) & 1u);
        ol.y = (float)((maskB >> (4 * j + 1)) & 1u);
        ol.z = (float)((maskB >> (4 * j + 2)) & 1u);
        ol.w = (float)((maskB >> (4 * j + 3)) & 1u);
        ((f32x4*)out_idx)[bB * 4 + (size_t)j] = oi;
        ((f32x4*)out_lab)[bB * 4 + (size_t)j] = ol;
    }
}

extern "C" void kernel_launch(void* const* d_in, const int* in_sizes, int n_in,
                              void* d_out, int out_size, void* d_ws, size_t ws_size,
                              hipStream_t stream) {
    const float* pred_logits = (const float*)d_in[0];
    const float* pred_disp   = (const float*)d_in[1];
    const float* targets     = (const float*)d_in[2];

    int B = in_sizes[0] / NQ;

    float* out_idx = (float*)d_out;              // indices [B, NQ] flat, first
    float* out_lab = out_idx + (size_t)B * NQ;   // labels  [B, NQ] flat, second

    const int threads = 256;
    const size_t Bh = ((size_t)B + 1) / 2;
    const size_t total = Bh * 4;                 // 4 lanes per row-pair
    const int blocks = (int)((total + threads - 1) / threads);
    hipLaunchKernelGGL(nearest_matcher_kernel, dim3(blocks), dim3(threads), 0, stream,
                       pred_logits, pred_disp, targets, out_idx, out_lab, B);
}